// Round 1
// baseline (252.910 us; speedup 1.0000x reference)
//
#include <hip/hip_runtime.h>
#include <stdint.h>

// Problem dims (fixed by reference)
#define BH   (8 * 4096)   // B*S tokens
#define HDIM 1024         // H
#define NIDX 65536
#define NSEG 8192         // M of the GEMM
#define KD   1024         // K
#define ND   1024         // N

typedef __bf16 bf16x8 __attribute__((ext_vector_type(8)));
typedef float  f32x4  __attribute__((ext_vector_type(4)));

__device__ __forceinline__ unsigned short f2bf(float f) {
  unsigned int u = __float_as_uint(f);
  u += 0x7fffu + ((u >> 16) & 1u);   // round-to-nearest-even
  return (unsigned short)(u >> 16);
}

__device__ __forceinline__ void async16(const void* g, void* l) {
  // global -> LDS direct DMA, 16B per lane; LDS dst = wave-uniform base + lane*16
  __builtin_amdgcn_global_load_lds(
      (const __attribute__((address_space(1))) void*)g,
      (__attribute__((address_space(3))) void*)l,
      16, 0, 0);
}

// ---------------- Kernel 1: W_dense fp32 -> bf16 ----------------
__global__ void convw_kernel(const float* __restrict__ W, unsigned short* __restrict__ Wb) {
  int i = (blockIdx.x * 256 + threadIdx.x) * 4;
  float4 v = *(const float4*)(W + i);
  ushort4 o;
  o.x = f2bf(v.x); o.y = f2bf(v.y); o.z = f2bf(v.z); o.w = f2bf(v.w);
  *(ushort4*)(Wb + i) = o;
}

// ---------------- Kernel 2: segment mean -> h (bf16), init out ----------------
// one block per segment; 256 threads, 4 cols each (float4)
__global__ void segmean_kernel(const float* __restrict__ hid,
                               const int* __restrict__ indices,
                               const int* __restrict__ seg,
                               unsigned short* __restrict__ hb,
                               float* __restrict__ out,
                               const float* __restrict__ b_proj) {
  const int g = blockIdx.x;
  const int t = threadIdx.x;

  // lower_bound(seg, g) and lower_bound(seg, g+1) — redundant per thread (cheap, broadcast loads)
  int lo = 0, hi = NIDX;
  while (lo < hi) { int mid = (lo + hi) >> 1; if (seg[mid] < g) lo = mid + 1; else hi = mid; }
  const int start = lo;
  hi = NIDX;
  while (lo < hi) { int mid = (lo + hi) >> 1; if (seg[mid] <= g) lo = mid + 1; else hi = mid; }
  const int end = lo;

  float4 acc = make_float4(0.f, 0.f, 0.f, 0.f);
  for (int i = start; i < end; ++i) {
    int r = indices[i];
    float4 v = *(const float4*)(hid + (size_t)r * HDIM + t * 4);
    acc.x += v.x; acc.y += v.y; acc.z += v.z; acc.w += v.w;
  }
  const float inv = 1.0f / fmaxf((float)(end - start), 1.0f);
  ushort4 o;
  o.x = f2bf(acc.x * inv); o.y = f2bf(acc.y * inv);
  o.z = f2bf(acc.z * inv); o.w = f2bf(acc.w * inv);
  *(ushort4*)(hb + (size_t)g * HDIM + t * 4) = o;

  if (t == 0) out[g] = b_proj[0];  // init with bias; GEMM epilogue atomicAdds partials
}

// ---------------- Kernel 3: fused GEMM + bias + erf-GELU + proj ----------------
// C tile 128x128, BK=32, 256 threads = 4 waves (2x2), wave tile 64x64 (4x4 MFMA 16x16x32)
__global__ void gemm_gelu_proj_kernel(const unsigned short* __restrict__ A,   // h  [NSEG,KD] bf16
                                      const unsigned short* __restrict__ Bw,  // W  [ND,KD]  bf16
                                      const float* __restrict__ b_dense,
                                      const float* __restrict__ w_proj,
                                      float* __restrict__ out) {
  __shared__ alignas(16) unsigned short As[128 * 32];
  __shared__ alignas(16) unsigned short Bs[128 * 32];

  const int tid  = threadIdx.x;
  const int lane = tid & 63;
  const int wave = tid >> 6;       // 0..3
  const int wm   = wave >> 1;      // 0..1
  const int wn   = wave & 1;       // 0..1
  const int m0   = blockIdx.x * 128;
  const int n0   = blockIdx.y * 128;
  const int lr   = lane & 15;      // fragment 16-index
  const int quad = lane >> 4;      // 0..3

  f32x4 acc[4][4];
#pragma unroll
  for (int mi = 0; mi < 4; ++mi)
#pragma unroll
    for (int ni = 0; ni < 4; ++ni) {
      acc[mi][ni][0] = 0.f; acc[mi][ni][1] = 0.f;
      acc[mi][ni][2] = 0.f; acc[mi][ni][3] = 0.f;
    }

  for (int kt = 0; kt < KD / 32; ++kt) {
    const int k0 = kt * 32;
    // stage A,B tiles: 512 chunks of 16B each; chunk c -> LDS byte c*16, row=c>>2, kchunk=c&3
#pragma unroll
    for (int j = 0; j < 2; ++j) {
      int c   = j * 256 + wave * 64 + lane;
      int row = c >> 2, kc = c & 3;
      const unsigned short* ga = A  + (size_t)(m0 + row) * KD + k0 + kc * 8;
      const unsigned short* gb = Bw + (size_t)(n0 + row) * KD + k0 + kc * 8;
      char* lbase_a = (char*)As + (j * 256 + wave * 64) * 16;  // wave-uniform base
      char* lbase_b = (char*)Bs + (j * 256 + wave * 64) * 16;
      async16(ga, lbase_a);
      async16(gb, lbase_b);
    }
    __syncthreads();

    bf16x8 af[4], bf_[4];
#pragma unroll
    for (int i = 0; i < 4; ++i) {
      af[i]  = *(const bf16x8*)(As + (wm * 64 + i * 16 + lr) * 32 + quad * 8);
      bf_[i] = *(const bf16x8*)(Bs + (wn * 64 + i * 16 + lr) * 32 + quad * 8);
    }
#pragma unroll
    for (int mi = 0; mi < 4; ++mi)
#pragma unroll
      for (int ni = 0; ni < 4; ++ni)
        acc[mi][ni] = __builtin_amdgcn_mfma_f32_16x16x32_bf16(af[mi], bf_[ni], acc[mi][ni], 0, 0, 0);
    __syncthreads();
  }

  // Epilogue: bias + exact gelu + weight by w_proj, reduce over this block's 128 cols, atomicAdd per row
#pragma unroll
  for (int mi = 0; mi < 4; ++mi) {
    float rp[4] = {0.f, 0.f, 0.f, 0.f};
#pragma unroll
    for (int ni = 0; ni < 4; ++ni) {
      int col  = n0 + wn * 64 + ni * 16 + lr;
      float bd = b_dense[col];
      float wp = w_proj[col];
#pragma unroll
      for (int r = 0; r < 4; ++r) {
        float v  = acc[mi][ni][r] + bd;
        float gl = 0.5f * v * (1.0f + erff(v * 0.70710678118654752f));
        rp[r] += gl * wp;
      }
    }
#pragma unroll
    for (int r = 0; r < 4; ++r) {
      float c = rp[r];
      c += __shfl_xor(c, 1);
      c += __shfl_xor(c, 2);
      c += __shfl_xor(c, 4);
      c += __shfl_xor(c, 8);
      if (lr == 0)
        atomicAdd(out + (m0 + wm * 64 + mi * 16 + quad * 4 + r), c);
    }
  }
}

extern "C" void kernel_launch(void* const* d_in, const int* in_sizes, int n_in,
                              void* d_out, int out_size, void* d_ws, size_t ws_size,
                              hipStream_t stream) {
  const float* hid     = (const float*)d_in[0];
  const int*   indices = (const int*)d_in[1];
  const int*   seg     = (const int*)d_in[2];
  const float* W_dense = (const float*)d_in[3];
  const float* b_dense = (const float*)d_in[4];
  const float* W_proj  = (const float*)d_in[5];
  const float* b_proj  = (const float*)d_in[6];
  float* out = (float*)d_out;

  // workspace layout: h_bf16 [NSEG*KD] (16 MiB) | W_bf16 [ND*KD] (2 MiB)
  unsigned short* hb = (unsigned short*)d_ws;
  unsigned short* Wb = (unsigned short*)((char*)d_ws + (size_t)NSEG * KD * sizeof(unsigned short));

  convw_kernel<<<dim3((ND * KD) / 1024), 256, 0, stream>>>(W_dense, Wb);
  segmean_kernel<<<dim3(NSEG), 256, 0, stream>>>(hid, indices, seg, hb, out, b_proj);
  gemm_gelu_proj_kernel<<<dim3(NSEG / 128, ND / 128), 256, 0, stream>>>(hb, Wb, b_dense, W_proj, out);
}

// Round 2
// 243.551 us; speedup vs baseline: 1.0384x; 1.0384x over previous
//
#include <hip/hip_runtime.h>
#include <stdint.h>

#define BH   (8 * 4096)
#define HDIM 1024
#define NIDX 65536
#define NSEG 8192
#define KD   1024
#define ND   1024

typedef __bf16 bf16x8 __attribute__((ext_vector_type(8)));
typedef float  f32x4  __attribute__((ext_vector_type(4)));

__device__ __forceinline__ unsigned short f2bf(float f) {
  unsigned int u = __float_as_uint(f);
  u += 0x7fffu + ((u >> 16) & 1u);   // RNE
  return (unsigned short)(u >> 16);
}

__device__ __forceinline__ void async16(const void* g, void* l) {
  __builtin_amdgcn_global_load_lds(
      (const __attribute__((address_space(1))) void*)g,
      (__attribute__((address_space(3))) void*)l,
      16, 0, 0);
}

// ---------------- Kernel 0: W_dense fp32 -> bf16 ----------------
__global__ void convw_kernel(const float* __restrict__ W, unsigned short* __restrict__ Wb) {
  int i = (blockIdx.x * 256 + threadIdx.x) * 4;
  float4 v = *(const float4*)(W + i);
  ushort4 o;
  o.x = f2bf(v.x); o.y = f2bf(v.y); o.z = f2bf(v.z); o.w = f2bf(v.w);
  *(ushort4*)(Wb + i) = o;
}

// ---------------- Kernel 1: segment boundaries ----------------
// seg sorted ascending. starts[g] = first i with seg[i] >= g; starts[NSEG] = NIDX.
__global__ void bounds_kernel(const int* __restrict__ seg, int* __restrict__ starts) {
  int i = blockIdx.x * 256 + threadIdx.x;
  if (i > NIDX) return;
  int prev = (i == 0) ? -1 : seg[i - 1];
  int cur  = (i == NIDX) ? NSEG : seg[i];
  for (int g = prev + 1; g <= cur; ++g) starts[g] = i;  // fills (prev, cur]
}

// ---------------- Kernel 2: segment mean -> h (bf16), init out ----------------
__global__ void segmean_kernel(const float* __restrict__ hid,
                               const int* __restrict__ indices,
                               const int* __restrict__ starts,
                               unsigned short* __restrict__ hb,
                               float* __restrict__ out,
                               const float* __restrict__ b_proj) {
  const int g = blockIdx.x;
  const int t = threadIdx.x;
  const int start = starts[g];
  const int end   = starts[g + 1];

  float4 acc = make_float4(0.f, 0.f, 0.f, 0.f);
  for (int i = start; i < end; ++i) {
    int r = indices[i];
    float4 v = *(const float4*)(hid + (size_t)r * HDIM + t * 4);
    acc.x += v.x; acc.y += v.y; acc.z += v.z; acc.w += v.w;
  }
  const float inv = 1.0f / fmaxf((float)(end - start), 1.0f);
  ushort4 o;
  o.x = f2bf(acc.x * inv); o.y = f2bf(acc.y * inv);
  o.z = f2bf(acc.z * inv); o.w = f2bf(acc.w * inv);
  *(ushort4*)(hb + (size_t)g * HDIM + t * 4) = o;

  if (t == 0) out[g] = b_proj[0];
}

// ---------------- Kernel 3: fused GEMM + bias + erf-GELU + proj ----------------
// C tile 128x64, BK=32, 256 threads = 4 waves (2x2), wave tile 64x32 (4x2 MFMA 16x16x32)
// LDS k-chunk swizzle: LDS slot (row, sl) holds global chunk sl ^ ((row>>1)&3)
// -> ds_read_b128 hits each 4-bank group with exactly 2 lanes (2-way aliasing = free).
__global__ void __launch_bounds__(256)
gemm_gelu_proj_kernel(const unsigned short* __restrict__ A,   // h  [NSEG,KD] bf16
                      const unsigned short* __restrict__ Bw,  // W  [ND,KD]  bf16
                      const float* __restrict__ b_dense,
                      const float* __restrict__ w_proj,
                      float* __restrict__ out) {
  __shared__ alignas(16) unsigned short As[128 * 32];  // 8 KiB
  __shared__ alignas(16) unsigned short Bs[64 * 32];   // 4 KiB

  const int tid  = threadIdx.x;
  const int lane = tid & 63;
  const int wave = tid >> 6;       // 0..3
  const int wm   = wave >> 1;      // 0..1 -> 64 rows
  const int wn   = wave & 1;       // 0..1 -> 32 cols
  const int m0   = blockIdx.x * 128;
  const int n0   = blockIdx.y * 64;
  const int lr   = lane & 15;
  const int quad = lane >> 4;      // 0..3

  f32x4 acc[4][2];
#pragma unroll
  for (int mi = 0; mi < 4; ++mi)
#pragma unroll
    for (int ni = 0; ni < 2; ++ni) {
      acc[mi][ni][0] = 0.f; acc[mi][ni][1] = 0.f;
      acc[mi][ni][2] = 0.f; acc[mi][ni][3] = 0.f;
    }

  for (int kt = 0; kt < KD / 32; ++kt) {
    const int k0 = kt * 32;
    // A: 512 chunks of 16B, B: 256 chunks; 256 threads -> 3 chunks/thread
#pragma unroll
    for (int j = 0; j < 2; ++j) {          // A chunks
      int c   = j * 256 + wave * 64 + lane;
      int row = c >> 2, sl = c & 3;
      int kcg = sl ^ ((row >> 1) & 3);     // swizzled global source chunk
      async16(A + (size_t)(m0 + row) * KD + k0 + kcg * 8,
              (char*)As + (j * 256 + wave * 64) * 16);
    }
    {                                       // B chunks
      int c   = wave * 64 + lane;
      int row = c >> 2, sl = c & 3;
      int kcg = sl ^ ((row >> 1) & 3);
      async16(Bw + (size_t)(n0 + row) * KD + k0 + kcg * 8,
              (char*)Bs + (wave * 64) * 16);
    }
    __syncthreads();

    bf16x8 af[4], bf_[2];
#pragma unroll
    for (int i = 0; i < 4; ++i) {
      int ra  = wm * 64 + i * 16 + lr;
      int sla = quad ^ ((ra >> 1) & 3);
      af[i] = *(const bf16x8*)(As + ra * 32 + sla * 8);
    }
#pragma unroll
    for (int i = 0; i < 2; ++i) {
      int rb  = wn * 32 + i * 16 + lr;
      int slb = quad ^ ((rb >> 1) & 3);
      bf_[i] = *(const bf16x8*)(Bs + rb * 32 + slb * 8);
    }
#pragma unroll
    for (int mi = 0; mi < 4; ++mi)
#pragma unroll
      for (int ni = 0; ni < 2; ++ni)
        acc[mi][ni] = __builtin_amdgcn_mfma_f32_16x16x32_bf16(af[mi], bf_[ni], acc[mi][ni], 0, 0, 0);
    __syncthreads();
  }

  // Epilogue: bias + exact erf-GELU + w_proj weighting, reduce over 64 block cols, atomicAdd per row
#pragma unroll
  for (int mi = 0; mi < 4; ++mi) {
    float rp[4] = {0.f, 0.f, 0.f, 0.f};
#pragma unroll
    for (int ni = 0; ni < 2; ++ni) {
      int col  = n0 + wn * 32 + ni * 16 + lr;
      float bd = b_dense[col];
      float wp = w_proj[col];
#pragma unroll
      for (int r = 0; r < 4; ++r) {
        float v  = acc[mi][ni][r] + bd;
        float gl = 0.5f * v * (1.0f + erff(v * 0.70710678118654752f));
        rp[r] += gl * wp;
      }
    }
#pragma unroll
    for (int r = 0; r < 4; ++r) {
      float c = rp[r];
      c += __shfl_xor(c, 1);
      c += __shfl_xor(c, 2);
      c += __shfl_xor(c, 4);
      c += __shfl_xor(c, 8);
      if (lr == 0)
        atomicAdd(out + (m0 + wm * 64 + mi * 16 + quad * 4 + r), c);
    }
  }
}

extern "C" void kernel_launch(void* const* d_in, const int* in_sizes, int n_in,
                              void* d_out, int out_size, void* d_ws, size_t ws_size,
                              hipStream_t stream) {
  const float* hid     = (const float*)d_in[0];
  const int*   indices = (const int*)d_in[1];
  const int*   seg     = (const int*)d_in[2];
  const float* W_dense = (const float*)d_in[3];
  const float* b_dense = (const float*)d_in[4];
  const float* W_proj  = (const float*)d_in[5];
  const float* b_proj  = (const float*)d_in[6];
  float* out = (float*)d_out;

  // ws layout: h_bf16 [NSEG*KD] (16 MiB) | W_bf16 [ND*KD] (2 MiB) | starts [NSEG+1]
  unsigned short* hb     = (unsigned short*)d_ws;
  unsigned short* Wb     = (unsigned short*)((char*)d_ws + (size_t)NSEG * KD * 2);
  int*            starts = (int*)((char*)d_ws + (size_t)NSEG * KD * 2 + (size_t)ND * KD * 2);

  convw_kernel<<<dim3((ND * KD) / 1024), 256, 0, stream>>>(W_dense, Wb);
  bounds_kernel<<<dim3((NIDX + 256) / 256), 256, 0, stream>>>(seg, starts);
  segmean_kernel<<<dim3(NSEG), 256, 0, stream>>>(hid, indices, starts, hb, out, b_proj);
  gemm_gelu_proj_kernel<<<dim3(NSEG / 128, ND / 64), 256, 0, stream>>>(hb, Wb, b_dense, W_proj, out);
}